// Round 7
// baseline (231.554 us; speedup 1.0000x reference)
//
#include <hip/hip_runtime.h>
#include <hip/hip_bf16.h>
#include <math.h>

// PillarHist: per-row 64-bin hist (count/mean_z/mean_r interleaved) -> Linear(192->64) -> BN(train) -> ReLU
// k0: build permuted bf16 B-fragments into d_ws + zero BN totals (64 replicas).
// k1: PERSISTENT waves (512 blocks, all resident), grid-stride over 16-row groups with software
//     pipelining (next group's uint2 z/w loads in flight during current group's MFMA). Wave-private
//     LDS hist via native ds_add_u32 fixed-point. NO block barriers; BN partials via 2 direct
//     u64 atomics per wave into 64 replicas.
// k3: sum replicas per block -> scale/shift -> apply BN+ReLU in-place (grid-stride).

typedef __attribute__((ext_vector_type(8))) short bf16x8;   // 8 bf16 = 4 VGPRs = 16 B
typedef __attribute__((ext_vector_type(4))) float f32x4;
typedef __attribute__((ext_vector_type(4))) int   i32x4;

#define ZMINF   (-3.0f)
#define INV_BIN 16.0f            // 1/BIN_SIZE (exact pow2)
#define HROWS   16               // rows per wave-group (MFMA M)
#define HPAD    196              // hist row stride (ints); 2-way b128 aliasing only
#define SZF     524288.0f        // 2^19 fixed-point scale for z/r sums
#define INV_SZF (1.0f / 524288.0f)
#define TSC     16777216.0f      // 2^24 fixed-point scale for BN totals
#define INV_TSC (1.0f / 16777216.0f)
#define REPS    64               // BN total replicas (contention/address = 2048/64 = 32)
#define NBLK1   512              // 2/CU guaranteed resident (3/CU by LDS) -> zero churn
#define NWAVES  (NBLK1 * 4)

__device__ __forceinline__ short f2bf(float f) {
    __hip_bfloat16 h = __float2bfloat16(f);   // RNE
    return __builtin_bit_cast(short, h);
}

// ---- k0: one block. Permuted W -> bf16 fragments (frag-major [s*4+t][lane][j]) + zero totals ----
__global__ __launch_bounds__(256)
void k0_prep(const float* __restrict__ W,                  // [64,192]
             short*       __restrict__ wsW,                // [24*64*8] bf16
             unsigned long long* __restrict__ totals)      // [REPS*128]
{
    const int tid = threadIdx.x;
    for (int e = tid; e < 24 * 64 * 8; e += 256) {
        const int j  = e & 7;
        const int ln = (e >> 3) & 63;
        const int st = e >> 9;                       // s*4+t
        const int s  = st >> 2, t = st & 3;
        const int k  = s * 32 + (ln >> 4) * 8 + j;   // planar k
        const int n  = t * 16 + (ln & 15);           // output channel
        const int wc = (k < 64) ? 3 * k
                     : (k < 128) ? 3 * (k - 64) + 1
                                 : 3 * (k - 128) + 2;
        wsW[e] = f2bf(W[n * 192 + wc]);
    }
    for (int e = tid; e < REPS * 128; e += 256) totals[e] = 0ull;
}

__global__ __launch_bounds__(256, 3)
void k1_hist_mfma(const uint2*  __restrict__ feat2,  // feat viewed as uint2; zw of (row,pt) at idx (row*64+pt)*2+1
                  const int*    __restrict__ nump,   // [M]
                  const bf16x8* __restrict__ wsWf,   // [24*64] B fragments (global, L2-hot)
                  const float*  __restrict__ bvec,   // [64]
                  float*        __restrict__ xout,   // [M,64] pre-BN x (d_out)
                  unsigned long long* __restrict__ totals, // [REPS*128] fixed-point sum | sumsq
                  int M, int G)                      // G = ceil(M/16) row-groups
{
    __shared__ int sH[4 * HROWS * HPAD];   // 50176 B -> 3 blocks/CU

    const int tid  = threadIdx.x;
    const int wave = tid >> 6;
    const int lane = tid & 63;
    const int col  = lane & 15;
    const int quad = lane >> 4;
    const int gw   = blockIdx.x * 4 + wave;   // global wave id

    int* hw = &sH[wave * HROWS * HPAD];
    float psum[4] = {0.f, 0.f, 0.f, 0.f};
    float psq[4]  = {0.f, 0.f, 0.f, 0.f};

    uint2 zw[HROWS];
    int   npv = 0;

    // ---- initial loads for first group (in flight while we zero LDS) ----
    int g = gw;
    if (g < G) {
        const int gbase = g * HROWS;
        #pragma unroll
        for (int u = 0; u < HROWS; ++u) {
            const int rc = min(gbase + u, M - 1);
            zw[u] = feat2[((size_t)rc * 64 + lane) * 2 + 1];
        }
        npv = nump[min(gbase + (lane & 15), M - 1)];
    }

    // ---- zero wave-private hist region (overlaps initial load latency) ----
    {
        i32x4* p4 = (i32x4*)hw;
        #pragma unroll
        for (int i = 0; i < 13; ++i) {
            const int idx = lane + i * 64;
            if (idx < (HROWS * HPAD) / 4) p4[idx] = i32x4{0, 0, 0, 0};
        }
    }
    __builtin_amdgcn_wave_barrier();

    for (; g < G; g += NWAVES) {
        const int gbase  = g * HROWS;
        const int nvalid = min(M - gbase, HROWS);

        // ---- consume zw/npv: native ds_add_u32 fixed-point hist ----
        #pragma unroll
        for (int u = 0; u < HROWS; ++u) {
            int np_u = __builtin_amdgcn_readlane(npv, u);
            np_u = (u < nvalid) ? np_u : 0;
            if (lane < np_u) {
                const float z  = __int_as_float((int)zw[u].x);
                const float rr = __int_as_float((int)zw[u].y);
                int bi = (int)((z - ZMINF) * INV_BIN);  // trunc, matches astype(int32)
                bi = min(max(bi, 0), 63);
                int* hrow = hw + u * HPAD;
                atomicAdd(hrow + bi, 1);
                atomicAdd(hrow + 64 + bi, (int)(z * SZF));
                atomicAdd(hrow + 128 + bi, (int)(rr * SZF));
            }
        }

        // ---- prefetch next group's loads (in flight during MFMA phase) ----
        const int gn = g + NWAVES;
        if (gn < G) {
            const int nb = gn * HROWS;
            #pragma unroll
            for (int u = 0; u < HROWS; ++u) {
                const int rc = min(nb + u, M - 1);
                zw[u] = feat2[((size_t)rc * 64 + lane) * 2 + 1];
            }
            npv = nump[min(nb + (lane & 15), M - 1)];
        }

        __builtin_amdgcn_wave_barrier();
        __threadfence_block();   // drain ds_adds before fragment reads (wave-private region)

        // ---- MFMA: A from LDS ints (means on the fly), B from global L2 (double-buffered regs) ----
        f32x4 acc[4] = {};
        bf16x8 bcur[4], bnxt[4];
        #pragma unroll
        for (int t = 0; t < 4; ++t) bcur[t] = wsWf[t * 64 + lane];   // s=0 frags

        const int* ar = hw + col * HPAD + quad * 8;   // A row m = col, k = quad*8+j (+32s)
        float c0[8], c1[8];
        #pragma unroll
        for (int s = 0; s < 6; ++s) {
            if (s < 5) {
                #pragma unroll
                for (int t = 0; t < 4; ++t) bnxt[t] = wsWf[((s + 1) * 4 + t) * 64 + lane];
            }
            const i32x4* ap = (const i32x4*)(ar + s * 32);
            const i32x4 a0 = ap[0], a1 = ap[1];
            const int iv[8] = {a0.x, a0.y, a0.z, a0.w, a1.x, a1.y, a1.z, a1.w};
            float av[8];
            if (s == 0) {
                #pragma unroll
                for (int j = 0; j < 8; ++j) { c0[j] = (float)iv[j]; av[j] = c0[j]; }
            } else if (s == 1) {
                #pragma unroll
                for (int j = 0; j < 8; ++j) { c1[j] = (float)iv[j]; av[j] = c1[j]; }
            } else if (s == 2) {
                #pragma unroll
                for (int j = 0; j < 8; ++j) {
                    c0[j] = __builtin_amdgcn_rcpf(c0[j] + 1e-5f) * INV_SZF;  // fold 2^-19 into rcp
                    av[j] = (float)iv[j] * c0[j];
                }
            } else if (s == 3) {
                #pragma unroll
                for (int j = 0; j < 8; ++j) {
                    c1[j] = __builtin_amdgcn_rcpf(c1[j] + 1e-5f) * INV_SZF;
                    av[j] = (float)iv[j] * c1[j];
                }
            } else if (s == 4) {
                #pragma unroll
                for (int j = 0; j < 8; ++j) av[j] = (float)iv[j] * c0[j];
            } else {
                #pragma unroll
                for (int j = 0; j < 8; ++j) av[j] = (float)iv[j] * c1[j];
            }
            bf16x8 af;
            #pragma unroll
            for (int j = 0; j < 8; ++j) af[j] = f2bf(av[j]);
            #pragma unroll
            for (int t = 0; t < 4; ++t)
                acc[t] = __builtin_amdgcn_mfma_f32_16x16x32_bf16(af, bcur[t], acc[t], 0, 0, 0);
            #pragma unroll
            for (int t = 0; t < 4; ++t) bcur[t] = bnxt[t];
        }

        // ---- epilogue: +bias, store x, BN partials. C/D: col=lane&15, row=quad*4+i ----
        #pragma unroll
        for (int t = 0; t < 4; ++t) {
            const float bias = bvec[t * 16 + col];
            #pragma unroll
            for (int i = 0; i < 4; ++i) {
                const int row = gbase + quad * 4 + i;
                if (row < M) {
                    const float xv = acc[t][i] + bias;
                    xout[(size_t)row * 64 + t * 16 + col] = xv;
                    psum[t] += xv;
                    psq[t]  += xv * xv;
                }
            }
        }

        // ---- re-zero hist region for next group (DS pipe in-order per wave; after A-reads) ----
        {
            i32x4* p4 = (i32x4*)hw;
            #pragma unroll
            for (int i = 0; i < 13; ++i) {
                const int idx = lane + i * 64;
                if (idx < (HROWS * HPAD) / 4) p4[idx] = i32x4{0, 0, 0, 0};
            }
        }
        __builtin_amdgcn_wave_barrier();
    }

    // ---- BN partials: quad-reduce; then channel == lane exactly; 2 direct u64 atomics per wave ----
    #pragma unroll
    for (int t = 0; t < 4; ++t) {
        psum[t] += __shfl_xor(psum[t], 16);
        psum[t] += __shfl_xor(psum[t], 32);
        psq[t]  += __shfl_xor(psq[t], 16);
        psq[t]  += __shfl_xor(psq[t], 32);
    }
    float myS = psum[0], myQ = psq[0];
    if (quad == 1) { myS = psum[1]; myQ = psq[1]; }
    if (quad == 2) { myS = psum[2]; myQ = psq[2]; }
    if (quad == 3) { myS = psum[3]; myQ = psq[3]; }
    unsigned long long* dst = totals + (gw & (REPS - 1)) * 128 + lane;   // channel = lane
    atomicAdd(dst,      (unsigned long long)(long long)(myS * TSC));
    atomicAdd(dst + 64, (unsigned long long)(long long)(myQ * TSC));
}

__global__ __launch_bounds__(256)
void k3_bn_apply(float4* __restrict__ x,
                 const unsigned long long* __restrict__ totals,
                 const float* __restrict__ gamma,
                 const float* __restrict__ beta,
                 float invM, int n4)
{
    __shared__ float sT[128];
    __shared__ float sa[64];
    __shared__ float sc[64];
    const int t = threadIdx.x;
    if (t < 128) {   // sum 64 replicas: 64 KB L2-hot per block, deterministic across blocks
        long long s = 0;
        #pragma unroll 8
        for (int rep = 0; rep < REPS; ++rep) s += (long long)totals[rep * 128 + t];
        sT[t] = (float)s * (invM * INV_TSC);
    }
    __syncthreads();
    if (t < 64) {
        const float mu   = sT[t];
        const float q    = sT[64 + t];
        const float var  = q - mu * mu;
        const float rstd = 1.0f / sqrtf(var + 1e-5f);
        const float a    = gamma[t] * rstd;
        sa[t] = a;
        sc[t] = beta[t] - mu * a;
    }
    __syncthreads();
    const int stride = gridDim.x * 256;
    for (int i = blockIdx.x * 256 + t; i < n4; i += stride) {
        const float4 a = ((const float4*)sa)[i & 15];   // 64 ch = 16 float4
        const float4 c = ((const float4*)sc)[i & 15];
        float4 v = x[i];
        v.x = fmaxf(fmaf(v.x, a.x, c.x), 0.f);
        v.y = fmaxf(fmaf(v.y, a.y, c.y), 0.f);
        v.z = fmaxf(fmaf(v.z, a.z, c.z), 0.f);
        v.w = fmaxf(fmaf(v.w, a.w, c.w), 0.f);
        x[i] = v;
    }
}

extern "C" void kernel_launch(void* const* d_in, const int* in_sizes, int n_in,
                              void* d_out, int out_size, void* d_ws, size_t ws_size,
                              hipStream_t stream) {
    const uint2*  feat2 = (const uint2*)d_in[0];   // [M,64,4] fp32 viewed as uint2 pairs
    const int*    nump  = (const int*)d_in[1];     // [M]
    // d_in[2] = coors (unused)
    const float*  W     = (const float*)d_in[3];   // [64,192]
    const float*  bvec  = (const float*)d_in[4];   // [64]
    const float*  gamma = (const float*)d_in[5];   // [64]
    const float*  beta  = (const float*)d_in[6];   // [64]

    const int M = in_sizes[1];
    float* xout = (float*)d_out;
    short* wsW  = (short*)d_ws;                                   // [24*64*8] bf16 B-fragments
    unsigned long long* totals =
        (unsigned long long*)((char*)d_ws + 24 * 64 * 8 * sizeof(short));  // [REPS*128] u64

    k0_prep<<<1, 256, 0, stream>>>(W, wsW, totals);

    const int G = (M + HROWS - 1) / HROWS;   // row-groups
    k1_hist_mfma<<<NBLK1, 256, 0, stream>>>(feat2, nump, (const bf16x8*)wsW, bvec, xout, totals, M, G);

    const int n4 = out_size / 4;
    const int nblk3 = (n4 + 256 * 16 - 1) / (256 * 16);
    k3_bn_apply<<<nblk3, 256, 0, stream>>>((float4*)d_out, totals, gamma, beta,
                                           1.0f / (float)M, n4);
}

// Round 8
// 202.351 us; speedup vs baseline: 1.1443x; 1.1443x over previous
//
#include <hip/hip_runtime.h>
#include <hip/hip_bf16.h>
#include <math.h>

// PillarHist: per-row 64-bin hist (count/mean_z/mean_r interleaved) -> Linear(192->64) -> BN(train) -> ReLU
// k0: build permuted bf16 B-fragments into d_ws + zero BN totals (16 replicas).
// k1 (non-persistent, 1563 blocks): wave-private LDS hist with PACKED fixed-point words
//     (z-word = count<<24 | biased z-payload ; r-word = biased r-payload) -> 2 ds_add_u32/point.
//     16-row z/w loads in ONE vmcnt round (uint2, 32 VGPRs, dead before MFMA -> no spill).
//     MFMA decodes counts/means from the packed words; B-frags from global L2, double-buffered.
//     No __syncthreads anywhere; per-wave BN partials -> 2 u64 atomics into 16 replicas.
// k3: sum replicas -> scale/shift -> apply BN+ReLU in-place (grid-stride).

typedef __attribute__((ext_vector_type(8))) short bf16x8;   // 8 bf16 = 4 VGPRs = 16 B
typedef __attribute__((ext_vector_type(4))) float f32x4;
typedef __attribute__((ext_vector_type(4))) int   i32x4;

#define ZMINF   (-3.0f)
#define INV_BIN 16.0f            // 1/BIN_SIZE (exact pow2)
#define HROWS   16               // rows per wave (MFMA M)
#define HPAD    132              // packed row stride (ints): [zword(64) | rword(64)] + 4 pad
#define QS      8192.0f          // 2^13 payload scale
#define INV_QS  (1.0f / 8192.0f)
#define PBIASF  65536.0f         // 2^16 payload bias (covers |z|<8; 64*max_payload < 2^24)
#define PBIASI  65536
#define CBIT    16777216         // 2^24 count increment (z-word only)
#define TSC     16777216.0f      // 2^24 fixed-point scale for BN totals
#define INV_TSC (1.0f / 16777216.0f)
#define REPS    16               // BN total replicas (12.5k wave-atomics / 2048 addrs ~ 6/addr)

__device__ __forceinline__ short f2bf(float f) {
    __hip_bfloat16 h = __float2bfloat16(f);   // RNE
    return __builtin_bit_cast(short, h);
}

// ---- k0: one block. Permuted W -> bf16 fragments (frag-major [s*4+t][lane][j]) + zero totals ----
__global__ __launch_bounds__(256)
void k0_prep(const float* __restrict__ W,                  // [64,192]
             short*       __restrict__ wsW,                // [24*64*8] bf16
             unsigned long long* __restrict__ totals)      // [REPS*128]
{
    const int tid = threadIdx.x;
    for (int e = tid; e < 24 * 64 * 8; e += 256) {
        const int j  = e & 7;
        const int ln = (e >> 3) & 63;
        const int st = e >> 9;                       // s*4+t
        const int s  = st >> 2, t = st & 3;
        const int k  = s * 32 + (ln >> 4) * 8 + j;   // planar k
        const int n  = t * 16 + (ln & 15);           // output channel
        const int wc = (k < 64) ? 3 * k
                     : (k < 128) ? 3 * (k - 64) + 1
                                 : 3 * (k - 128) + 2;
        wsW[e] = f2bf(W[n * 192 + wc]);
    }
    for (int e = tid; e < REPS * 128; e += 256) totals[e] = 0ull;
}

__global__ __launch_bounds__(256, 4)
void k1_hist_mfma(const uint2*  __restrict__ feat2,  // feat as uint2; zw of (row,pt) at (row*64+pt)*2+1
                  const int*    __restrict__ nump,   // [M]
                  const bf16x8* __restrict__ wsWf,   // [24*64] B fragments (global, L2-hot)
                  const float*  __restrict__ bvec,   // [64]
                  float*        __restrict__ xout,   // [M,64] pre-BN x (d_out)
                  unsigned long long* __restrict__ totals, // [REPS*128] fixed-point sum | sumsq
                  int M)
{
    __shared__ int sH[4 * HROWS * HPAD];   // 33792 B -> 4 blocks/CU

    const int tid  = threadIdx.x;
    const int wave = tid >> 6;
    const int lane = tid & 63;
    const int col  = lane & 15;
    const int quad = lane >> 4;

    const int gbase = (blockIdx.x * 4 + wave) * HROWS;
    int* hw = &sH[wave * HROWS * HPAD];
    float psum[4] = {0.f, 0.f, 0.f, 0.f};
    float psq[4]  = {0.f, 0.f, 0.f, 0.f};

    if (gbase < M) {
        // ---- 16 rows of z/w in ONE load batch (uint2 = 8 B/lane; 32 VGPRs, dead before MFMA) ----
        uint2 zw[HROWS];
        const int npv = nump[min(gbase + (lane & 15), M - 1)];   // lane-distributed, readlane below
        #pragma unroll
        for (int u = 0; u < HROWS; ++u) {
            const int rc = min(gbase + u, M - 1);
            zw[u] = feat2[((size_t)rc * 64 + lane) * 2 + 1];
        }

        // ---- zero wave-private hist region (overlaps load latency) ----
        {
            i32x4* p4 = (i32x4*)hw;
            #pragma unroll
            for (int i = 0; i < 9; ++i) {
                const int idx = lane + i * 64;
                if (idx < (HROWS * HPAD) / 4) p4[idx] = i32x4{0, 0, 0, 0};
            }
        }
        __builtin_amdgcn_wave_barrier();

        // ---- packed hist: 2 native ds_add_u32 per point ----
        #pragma unroll
        for (int u = 0; u < HROWS; ++u) {
            int np_u = __builtin_amdgcn_readlane(npv, u);
            np_u = (gbase + u < M) ? np_u : 0;                  // uniform tail guard
            if (lane < np_u) {
                const float z  = __int_as_float((int)zw[u].x);
                const float rr = __int_as_float((int)zw[u].y);
                int bi = (int)((z - ZMINF) * INV_BIN);          // trunc, matches astype(int32)
                bi = min(max(bi, 0), 63);
                int* hrow = hw + u * HPAD;
                atomicAdd(hrow + bi,      CBIT + PBIASI + (int)(z * QS));   // count | biased z
                atomicAdd(hrow + 64 + bi, PBIASI + (int)(rr * QS));         // biased r
            }
        }
        __builtin_amdgcn_wave_barrier();
        __threadfence_block();   // drain ds ops before fragment reads (wave-private region)

        // ---- MFMA: decode A-frags from packed words; B from global L2 (double-buffered regs) ----
        f32x4 acc[4] = {};
        bf16x8 bcur[4], bnxt[4];
        #pragma unroll
        for (int t = 0; t < 4; ++t) bcur[t] = wsWf[t * 64 + lane];   // s=0 frags

        const int* ar = hw + col * HPAD;   // A row m = col
        int   z0[8], z1[8];                // cached z-words (s0/s1), reused for means (s2/s3)
        float cnt0[8], cnt1[8], rcp0[8], rcp1[8];
        #pragma unroll
        for (int s = 0; s < 6; ++s) {
            if (s < 5) {
                #pragma unroll
                for (int t = 0; t < 4; ++t) bnxt[t] = wsWf[((s + 1) * 4 + t) * 64 + lane];
            }
            float av[8];
            if (s == 0 || s == 1) {
                // read z-words for bins quad*8 (+32 for s=1); av = count
                const i32x4* ap = (const i32x4*)(ar + s * 32 + quad * 8);
                const i32x4 a0 = ap[0], a1 = ap[1];
                int* zc = (s == 0) ? z0 : z1;
                float* cc = (s == 0) ? cnt0 : cnt1;
                zc[0]=a0.x; zc[1]=a0.y; zc[2]=a0.z; zc[3]=a0.w;
                zc[4]=a1.x; zc[5]=a1.y; zc[6]=a1.z; zc[7]=a1.w;
                #pragma unroll
                for (int j = 0; j < 8; ++j) { cc[j] = (float)(zc[j] >> 24); av[j] = cc[j]; }
            } else if (s == 2 || s == 3) {
                // no ds_read: mean_z from cached z-words; build reciprocals (2^-13 folded)
                const int*   zc = (s == 2) ? z0 : z1;
                const float* cc = (s == 2) ? cnt0 : cnt1;
                float* rp = (s == 2) ? rcp0 : rcp1;
                #pragma unroll
                for (int j = 0; j < 8; ++j) {
                    rp[j] = __builtin_amdgcn_rcpf(cc[j] + 1e-5f) * INV_QS;
                    const float pay = (float)(zc[j] & 0xFFFFFF);            // exact (<2^24)
                    av[j] = (pay - cc[j] * PBIASF) * rp[j];
                }
            } else {
                // read r-words at plane offset 64 (+32 for s=5); mean_r with cached count/rcp
                const i32x4* ap = (const i32x4*)(ar + 64 + (s - 4) * 32 + quad * 8);
                const i32x4 a0 = ap[0], a1 = ap[1];
                const int rv[8] = {a0.x, a0.y, a0.z, a0.w, a1.x, a1.y, a1.z, a1.w};
                const float* cc = (s == 4) ? cnt0 : cnt1;
                const float* rp = (s == 4) ? rcp0 : rcp1;
                #pragma unroll
                for (int j = 0; j < 8; ++j)
                    av[j] = ((float)rv[j] - cc[j] * PBIASF) * rp[j];
            }
            bf16x8 af;
            #pragma unroll
            for (int j = 0; j < 8; ++j) af[j] = f2bf(av[j]);
            #pragma unroll
            for (int t = 0; t < 4; ++t)
                acc[t] = __builtin_amdgcn_mfma_f32_16x16x32_bf16(af, bcur[t], acc[t], 0, 0, 0);
            #pragma unroll
            for (int t = 0; t < 4; ++t) bcur[t] = bnxt[t];
        }

        // ---- epilogue: +bias, store x, BN partials. C/D: col=lane&15, row=quad*4+i ----
        #pragma unroll
        for (int t = 0; t < 4; ++t) {
            const float bias = bvec[t * 16 + col];
            #pragma unroll
            for (int i = 0; i < 4; ++i) {
                const int row = gbase + quad * 4 + i;
                if (row < M) {
                    const float xv = acc[t][i] + bias;
                    xout[(size_t)row * 64 + t * 16 + col] = xv;
                    psum[t] += xv;
                    psq[t]  += xv * xv;
                }
            }
        }
    }

    // ---- BN partials: quad-reduce; channel == lane; 2 direct u64 atomics per wave ----
    #pragma unroll
    for (int t = 0; t < 4; ++t) {
        psum[t] += __shfl_xor(psum[t], 16);
        psum[t] += __shfl_xor(psum[t], 32);
        psq[t]  += __shfl_xor(psq[t], 16);
        psq[t]  += __shfl_xor(psq[t], 32);
    }
    float myS = psum[0], myQ = psq[0];
    if (quad == 1) { myS = psum[1]; myQ = psq[1]; }
    if (quad == 2) { myS = psum[2]; myQ = psq[2]; }
    if (quad == 3) { myS = psum[3]; myQ = psq[3]; }
    const int gw = blockIdx.x * 4 + wave;
    unsigned long long* dst = totals + (gw & (REPS - 1)) * 128 + lane;   // channel = lane
    atomicAdd(dst,      (unsigned long long)(long long)(myS * TSC));
    atomicAdd(dst + 64, (unsigned long long)(long long)(myQ * TSC));
}

__global__ __launch_bounds__(256)
void k3_bn_apply(float4* __restrict__ x,
                 const unsigned long long* __restrict__ totals,
                 const float* __restrict__ gamma,
                 const float* __restrict__ beta,
                 float invM, int n4)
{
    __shared__ float sT[128];
    __shared__ float sa[64];
    __shared__ float sc[64];
    const int t = threadIdx.x;
    if (t < 128) {   // sum replicas: 16 KB L2-hot per block, deterministic across blocks
        long long s = 0;
        #pragma unroll
        for (int rep = 0; rep < REPS; ++rep) s += (long long)totals[rep * 128 + t];
        sT[t] = (float)s * (invM * INV_TSC);
    }
    __syncthreads();
    if (t < 64) {
        const float mu   = sT[t];
        const float q    = sT[64 + t];
        const float var  = q - mu * mu;
        const float rstd = 1.0f / sqrtf(var + 1e-5f);
        const float a    = gamma[t] * rstd;
        sa[t] = a;
        sc[t] = beta[t] - mu * a;
    }
    __syncthreads();
    const int stride = gridDim.x * 256;
    for (int i = blockIdx.x * 256 + t; i < n4; i += stride) {
        const float4 a = ((const float4*)sa)[i & 15];   // 64 ch = 16 float4
        const float4 c = ((const float4*)sc)[i & 15];
        float4 v = x[i];
        v.x = fmaxf(fmaf(v.x, a.x, c.x), 0.f);
        v.y = fmaxf(fmaf(v.y, a.y, c.y), 0.f);
        v.z = fmaxf(fmaf(v.z, a.z, c.z), 0.f);
        v.w = fmaxf(fmaf(v.w, a.w, c.w), 0.f);
        x[i] = v;
    }
}

extern "C" void kernel_launch(void* const* d_in, const int* in_sizes, int n_in,
                              void* d_out, int out_size, void* d_ws, size_t ws_size,
                              hipStream_t stream) {
    const uint2*  feat2 = (const uint2*)d_in[0];   // [M,64,4] fp32 viewed as uint2 pairs
    const int*    nump  = (const int*)d_in[1];     // [M]
    // d_in[2] = coors (unused)
    const float*  W     = (const float*)d_in[3];   // [64,192]
    const float*  bvec  = (const float*)d_in[4];   // [64]
    const float*  gamma = (const float*)d_in[5];   // [64]
    const float*  beta  = (const float*)d_in[6];   // [64]

    const int M = in_sizes[1];
    float* xout = (float*)d_out;
    short* wsW  = (short*)d_ws;                                   // [24*64*8] bf16 B-fragments
    unsigned long long* totals =
        (unsigned long long*)((char*)d_ws + 24 * 64 * 8 * sizeof(short));  // [REPS*128] u64

    k0_prep<<<1, 256, 0, stream>>>(W, wsW, totals);

    const int nblk = (M + 4 * HROWS - 1) / (4 * HROWS);   // 64 rows/block
    k1_hist_mfma<<<nblk, 256, 0, stream>>>(feat2, nump, (const bf16x8*)wsW, bvec, xout, totals, M);

    const int n4 = out_size / 4;
    const int nblk3 = (n4 + 256 * 16 - 1) / (256 * 16);
    k3_bn_apply<<<nblk3, 256, 0, stream>>>((float4*)d_out, totals, gamma, beta,
                                           1.0f / (float)M, n4);
}